// Round 16
// baseline (283.095 us; speedup 1.0000x reference)
//
#include <hip/hip_runtime.h>
#include <hip/hip_fp16.h>
#include <math.h>

// GCN 2-layer (DGL GraphConv norm='both'). *** DIAGNOSTIC ROUND ***
// r15 structure (155.9us; r14 155.3 champion) with the five non-fragile
// kernels amplified x4 in-place (idempotent rep loops + memory clobber) so
// their true per-kernel costs surface above the ~44us harness-fill floor in
// rocprof's top-5 (real cost = displayed dur / 4). K1 is regalloc-fragile
// (r7/r10 spills) and stays byte-identical; its cost = total residual.
// rowscan is made OUT-OF-PLACE (dhist -> dscan) so re-running it is
// idempotent; partition/finalize re-derive all LDS state per rep.
// Numerics identical to r15 (every rep writes the same values).
#define BS 256
#define EPB 2048    // edges per hist/partition block (8 iters of 256)
#define REPS 4      // diagnostic amplification factor

// ---- K1: per-block dst+src hists + featw1 (r6 verbatim, NOT amplified) ----
__global__ __launch_bounds__(256, 4)
void histA_featw1_kernel(const int* __restrict__ src, const int* __restrict__ dst,
                         const float* __restrict__ feat, const float* __restrict__ W1,
                         int* __restrict__ dhist,
                         __half* __restrict__ featp,
                         int E, int N, int NB, int T, int M) {
    __shared__ float4 ftile[64 * 16];   // 64 feat rows (16KB)
    __shared__ int histD[256];
    __shared__ int histS[256];
    int tid = threadIdx.x;
    if ((int)blockIdx.x < T) {
        histD[tid] = 0; histS[tid] = 0;
        __syncthreads();
        int base = blockIdx.x * EPB;
        #pragma unroll
        for (int it = 0; it < EPB / BS; it++) {
            int e = base + it * BS + tid;
            if (e < E) {
                atomicAdd(&histD[dst[e] >> 8], 1);
                atomicAdd(&histS[src[e] >> 8], 1);
            }
        }
        __syncthreads();
        if (tid < NB) {
            dhist[tid * T + (int)blockIdx.x] = histD[tid];
            dhist[M + tid * T + (int)blockIdx.x] = histS[tid];
        }
    } else {
        int lane = tid & 63;
        int wave = tid >> 6;
        // W1 column for this lane: 64 named scalars (static -> registers).
        #define WD(i) float wv##i = W1[(i) * 64 + lane];
        WD(0)  WD(1)  WD(2)  WD(3)  WD(4)  WD(5)  WD(6)  WD(7)
        WD(8)  WD(9)  WD(10) WD(11) WD(12) WD(13) WD(14) WD(15)
        WD(16) WD(17) WD(18) WD(19) WD(20) WD(21) WD(22) WD(23)
        WD(24) WD(25) WD(26) WD(27) WD(28) WD(29) WD(30) WD(31)
        WD(32) WD(33) WD(34) WD(35) WD(36) WD(37) WD(38) WD(39)
        WD(40) WD(41) WD(42) WD(43) WD(44) WD(45) WD(46) WD(47)
        WD(48) WD(49) WD(50) WD(51) WD(52) WD(53) WD(54) WD(55)
        WD(56) WD(57) WD(58) WD(59) WD(60) WD(61) WD(62) WD(63)
        #undef WD
        // stage 64 feat rows into LDS (coalesced, 4 float4/thread)
        int rBase = ((int)blockIdx.x - T) * 64;
        const float4* feat4 = (const float4*)feat;
        int maxF4 = N * 16 - 1;
        #pragma unroll
        for (int it = 0; it < 4; it++) {
            int idx = it * BS + tid;
            ftile[idx] = feat4[min(rBase * 16 + idx, maxF4)];
        }
        __syncthreads();
        // 16 rows per wave; per row: 16 b128 broadcast reads + 64 FMA
        #pragma unroll 1
        for (int rr = 0; rr < 16; rr++) {
            int r = wave * 16 + rr;
            const float4* ft = &ftile[r * 16];
            float a0 = 0.0f, a1 = 0.0f, a2 = 0.0f, a3 = 0.0f;
            #define RK(k4, wA, wB, wC, wD_) { float4 f = ft[k4]; \
                a0 = fmaf(f.x, wA, a0); a1 = fmaf(f.y, wB, a1); \
                a2 = fmaf(f.z, wC, a2); a3 = fmaf(f.w, wD_, a3); }
            RK(0,  wv0,  wv1,  wv2,  wv3)  RK(1,  wv4,  wv5,  wv6,  wv7)
            RK(2,  wv8,  wv9,  wv10, wv11) RK(3,  wv12, wv13, wv14, wv15)
            RK(4,  wv16, wv17, wv18, wv19) RK(5,  wv20, wv21, wv22, wv23)
            RK(6,  wv24, wv25, wv26, wv27) RK(7,  wv28, wv29, wv30, wv31)
            RK(8,  wv32, wv33, wv34, wv35) RK(9,  wv36, wv37, wv38, wv39)
            RK(10, wv40, wv41, wv42, wv43) RK(11, wv44, wv45, wv46, wv47)
            RK(12, wv48, wv49, wv50, wv51) RK(13, wv52, wv53, wv54, wv55)
            RK(14, wv56, wv57, wv58, wv59) RK(15, wv60, wv61, wv62, wv63)
            #undef RK
            int rowg = rBase + r;
            if (rowg < N)
                featp[(size_t)rowg * 64 + lane] = __float2half((a0 + a1) + (a2 + a3));
        }
    }
}

// ---- K2: one wave per dhist row: OUT-OF-PLACE exclusive scan (x REPS) ----
__global__ void rowscan_kernel(const int* __restrict__ dhist, int* __restrict__ dscan,
                               int* __restrict__ rowTotal, int T, int R) {
    int gw = (int)((blockIdx.x * blockDim.x + threadIdx.x) >> 6);
    int lane = threadIdx.x & 63;
    if (gw >= R) return;
    const int* row = dhist + (size_t)gw * T;
    int* rowo = dscan + (size_t)gw * T;
    #pragma unroll 1
    for (int rep = 0; rep < REPS; rep++) {
        asm volatile("" ::: "memory");
        int carry = 0;
        int nch = (T + 63) >> 6;
        for (int c = 0; c < nch; c++) {
            int idx = c * 64 + lane;
            int v = (idx < T) ? row[idx] : 0;
            int inc = v;
            #pragma unroll
            for (int off = 1; off < 64; off <<= 1) {
                int u = __shfl_up(inc, off, 64);
                if (lane >= off) inc += u;
            }
            if (idx < T) rowo[idx] = inc - v + carry;   // exclusive within row
            carry += __shfl(inc, 63, 64);               // broadcast chunk total
        }
        if (lane == 0) rowTotal[gw] = carry;
    }
}

// ---- K3: partition (x REPS): binBase scan + single-pass dual scatter ----
__global__ void partition_kernel(const int* __restrict__ src, const int* __restrict__ dst,
                                 const int* __restrict__ dscan, const int* __restrict__ rowTotal,
                                 int* __restrict__ packed, unsigned char* __restrict__ srcPartB,
                                 int E, int NB, int T, int M) {
    __shared__ int sd[256], ss[256];
    __shared__ int darr[256], sarr[256];
    int tid = threadIdx.x;
    int b = blockIdx.x;
    #pragma unroll 1
    for (int rep = 0; rep < REPS; rep++) {
        asm volatile("" ::: "memory");
        int vd = (tid < NB) ? rowTotal[tid] : 0;
        int vs = (tid < NB) ? rowTotal[NB + tid] : 0;
        sd[tid] = vd; ss[tid] = vs;
        __syncthreads();
        for (int off = 1; off < 256; off <<= 1) {
            int ud = (tid >= off) ? sd[tid - off] : 0;
            int us = (tid >= off) ? ss[tid - off] : 0;
            __syncthreads();
            sd[tid] += ud; ss[tid] += us;
            __syncthreads();
        }
        darr[tid] = (tid < NB) ? ((sd[tid] - vd) + dscan[tid * T + b]) : 0;
        sarr[tid] = (tid < NB) ? ((ss[tid] - vs) + dscan[M + tid * T + b]) : 0;
        __syncthreads();
        int base = b * EPB;
        #pragma unroll
        for (int it = 0; it < EPB / BS; it++) {
            int e = base + it * BS + tid;
            if (e < E) {
                int d = dst[e], s2 = src[e];
                int pos = atomicAdd(&darr[d >> 8], 1);
                packed[pos] = s2 | ((d & 255) << 17);
                int pos2 = atomicAdd(&sarr[s2 >> 8], 1);
                srcPartB[pos2] = (unsigned char)(s2 & 255);
            }
        }
        __syncthreads();
    }
}

// ---- K4: finalize (x REPS): dst bins -> CSR; src bins -> out_deg ----
__global__ void finalize_kernel(const int* __restrict__ rowTotal,
                                const int* __restrict__ packed,
                                const unsigned char* __restrict__ srcPartB,
                                int* __restrict__ csr_src, int* __restrict__ in_deg,
                                int* __restrict__ row_start, int* __restrict__ out_deg,
                                int N, int NB) {
    __shared__ int sd[256], ss[256], td_[256], ts_[256];
    __shared__ int hist[256];
    __shared__ int sc[256];
    int tid = threadIdx.x;
    int b = blockIdx.x;
    #pragma unroll 1
    for (int rep = 0; rep < REPS; rep++) {
        asm volatile("" ::: "memory");
        int vd = (tid < NB) ? rowTotal[tid] : 0;
        int vs = (tid < NB) ? rowTotal[NB + tid] : 0;
        sd[tid] = vd; ss[tid] = vs; td_[tid] = vd; ts_[tid] = vs;
        __syncthreads();
        for (int off = 1; off < 256; off <<= 1) {
            int ud = (tid >= off) ? sd[tid - off] : 0;
            int us = (tid >= off) ? ss[tid - off] : 0;
            __syncthreads();
            sd[tid] += ud; ss[tid] += us;
            __syncthreads();
        }
        if (b < NB) {
            int lo = sd[b] - td_[b];       // exclusive binBase
            int hi = sd[b];                // inclusive = next bin's base
            hist[tid] = 0; __syncthreads();
            for (int i = lo + tid; i < hi; i += BS)
                atomicAdd(&hist[(packed[i] >> 17) & 255], 1);
            __syncthreads();
            int v = hist[tid];
            sc[tid] = v; __syncthreads();
            for (int off = 1; off < 256; off <<= 1) {
                int u = (tid >= off) ? sc[tid - off] : 0; __syncthreads();
                sc[tid] += u; __syncthreads();
            }
            int ex = sc[tid] - v;          // exclusive within bin
            int n = b * 256 + tid;
            if (n < N) { in_deg[n] = v; row_start[n] = lo + ex; }
            sc[tid] = lo + ex;             // becomes the scatter cursor
            __syncthreads();
            for (int i = lo + tid; i < hi; i += BS) {
                int pv = packed[i];
                int pos = atomicAdd(&sc[(pv >> 17) & 255], 1);
                csr_src[pos] = pv & 0x1FFFF;
            }
        } else {
            int sb = b - NB;
            int lo = ss[sb] - ts_[sb];
            int hi = ss[sb];
            hist[tid] = 0; __syncthreads();
            for (int i = lo + tid; i < hi; i += BS)
                atomicAdd(&hist[srcPartB[i]], 1);
            __syncthreads();
            int n = sb * 256 + tid;
            if (n < N) out_deg[n] = hist[tid];
        }
        __syncthreads();
    }
}

// ---- K5: agg1 (x REPS): one wave/node; per-edge out_norm ----
__global__ void csr_agg1_kernel(const int* __restrict__ row_start, const int* __restrict__ in_deg,
                                const int* __restrict__ csr_src, const int* __restrict__ out_deg,
                                const __half* __restrict__ featp,
                                const float* __restrict__ b1, const float* __restrict__ W2,
                                float* __restrict__ s_buf, int N) {
    int gid = blockIdx.x * blockDim.x + threadIdx.x;
    int n = gid >> 6;
    if (n >= N) return;
    int lane = threadIdx.x & 63;
    int g = lane >> 3;   // edge slot within batch of 8
    int l = lane & 7;    // feature chunk: features [8l, 8l+8)
    #pragma unroll 1
    for (int rep = 0; rep < REPS; rep++) {
        asm volatile("" ::: "memory");
        int start = row_start[n];
        int deg = in_deg[n];
        float acc[8] = {0, 0, 0, 0, 0, 0, 0, 0};
        const uint4* fp4 = (const uint4*)featp;
        for (int j = 0; j < deg; j += 16) {
            int e0 = j + g;
            int e1 = j + 8 + g;
            bool p0 = e0 < deg;
            bool p1 = e1 < deg;
            int sn0 = p0 ? csr_src[start + e0] : 0;
            int sn1 = p1 ? csr_src[start + e1] : 0;
            uint4 q0 = {0, 0, 0, 0}, q1 = {0, 0, 0, 0};
            float on0 = 0.0f, on1 = 0.0f;
            if (p0) { q0 = fp4[(size_t)sn0 * 8 + l]; on0 = rsqrtf(fmaxf((float)out_deg[sn0], 1.0f)); }
            if (p1) { q1 = fp4[(size_t)sn1 * 8 + l]; on1 = rsqrtf(fmaxf((float)out_deg[sn1], 1.0f)); }
            const __half2* h0 = (const __half2*)&q0;
            const __half2* h1 = (const __half2*)&q1;
            #pragma unroll
            for (int c = 0; c < 4; c++) {
                float2 f0 = __half22float2(h0[c]);
                float2 f1 = __half22float2(h1[c]);
                acc[2 * c]     += on0 * f0.x + on1 * f1.x;
                acc[2 * c + 1] += on0 * f0.y + on1 * f1.y;
            }
        }
        #pragma unroll
        for (int off = 8; off < 64; off <<= 1) {
            #pragma unroll
            for (int c = 0; c < 8; c++)
                acc[c] += __shfl_xor(acc[c], off, 64);
        }
        float inn = rsqrtf(fmaxf((float)deg, 1.0f));
        float v = 0.0f;
        #pragma unroll
        for (int c = 0; c < 8; c++) {
            float h = fmaxf(inn * acc[c] + b1[l * 8 + c], 0.0f);
            v += h * W2[l * 8 + c];
        }
        #pragma unroll
        for (int off = 1; off < 8; off <<= 1)
            v += __shfl_xor(v, off, 64);
        if (lane == 0)
            s_buf[n] = rsqrtf(fmaxf((float)out_deg[n], 1.0f)) * v;
    }
}

// ---- K6: agg2 (x REPS): 16 lanes/node -> sigmoid ----
__global__ void csr_agg2_kernel(const int* __restrict__ row_start, const int* __restrict__ in_deg,
                                const int* __restrict__ csr_src,
                                const float* __restrict__ s_buf, const float* __restrict__ b2,
                                float* __restrict__ out, int N) {
    int gid = blockIdx.x * blockDim.x + threadIdx.x;
    int n = gid >> 4;
    if (n >= N) return;
    int sub = gid & 15;
    #pragma unroll 1
    for (int rep = 0; rep < REPS; rep++) {
        asm volatile("" ::: "memory");
        int start = row_start[n];
        int deg = in_deg[n];
        float a = 0.0f;
        for (int j = sub; j < deg; j += 32) {
            int j1 = j + 16;
            int i0 = csr_src[start + j];
            int i1 = (j1 < deg) ? csr_src[start + j1] : 0;
            float v0 = s_buf[i0];
            float v1 = (j1 < deg) ? s_buf[i1] : 0.0f;
            a += v0 + v1;
        }
        #pragma unroll
        for (int off = 1; off < 16; off <<= 1)
            a += __shfl_xor(a, off, 64);
        if (sub == 0) {
            float x = rsqrtf(fmaxf((float)deg, 1.0f)) * a + b2[0];
            out[n] = 1.0f / (1.0f + expf(-x));
        }
    }
}

extern "C" void kernel_launch(void* const* d_in, const int* in_sizes, int n_in,
                              void* d_out, int out_size, void* d_ws, size_t ws_size,
                              hipStream_t stream) {
    const float* feat = (const float*)d_in[0];
    const float* W1   = (const float*)d_in[1];
    const float* b1   = (const float*)d_in[2];
    const float* W2   = (const float*)d_in[3];
    const float* b2   = (const float*)d_in[4];
    const int* src = (const int*)d_in[5];
    const int* dst = (const int*)d_in[6];
    float* out = (float*)d_out;

    const int N  = in_sizes[0] / 64;       // 50000
    const int E  = in_sizes[5];            // 800000
    const int NB = (N + 255) >> 8;         // 196 bins of 256 nodes
    const int T  = (E + EPB - 1) / EPB;    // 391 hist/partition blocks
    const int M  = NB * T;                 // per-side flat (bin, block) counts
    const int R  = 2 * NB;                 // dhist rows (dst bins then src bins)

    // workspace: rowTotal | per-node | dhist | dscan | edge arrays | fp16 | f32
    int* wsi = (int*)d_ws;
    int* rowTotal    = wsi;                          // 2*NB (written by rowscan)
    int* in_deg      = rowTotal + R;                 // N
    int* row_start   = in_deg + N;                   // N
    int* out_deg     = row_start + N;                // N (fully written by finalize)
    int* dhist       = out_deg + N;                  // 2*M (written by K1)
    int* dscan       = dhist + 2 * M;                // 2*M (written by rowscan)
    int* packed      = dscan + 2 * M;                // E
    int* csr_src     = packed + E;                   // E
    unsigned char* srcPartB = (unsigned char*)(csr_src + E);      // E bytes
    size_t int_bytes = ((size_t)R + 3 * (size_t)N + 4 * (size_t)M + 2 * (size_t)E) * sizeof(int)
                     + (size_t)E;
    size_t half_off  = (int_bytes + 15) & ~(size_t)15;
    __half* featp = (__half*)((char*)d_ws + half_off);            // 64N fp16
    float* s_buf  = (float*)((char*)d_ws + half_off + (size_t)64 * N * sizeof(__half));

    histA_featw1_kernel<<<T + (N + 63) / 64, BS, 0, stream>>>(
        src, dst, feat, W1, dhist, featp, E, N, NB, T, M);
    rowscan_kernel<<<(R * 64 + BS - 1) / BS, BS, 0, stream>>>(dhist, dscan, rowTotal, T, R);
    partition_kernel<<<T, BS, 0, stream>>>(
        src, dst, dscan, rowTotal, packed, srcPartB, E, NB, T, M);
    finalize_kernel<<<2 * NB, BS, 0, stream>>>(
        rowTotal, packed, srcPartB, csr_src, in_deg, row_start, out_deg, N, NB);
    csr_agg1_kernel<<<(int)(((size_t)N * 64 + BS - 1) / BS), BS, 0, stream>>>(
        row_start, in_deg, csr_src, out_deg, featp, b1, W2, s_buf, N);
    csr_agg2_kernel<<<(int)(((size_t)N * 16 + BS - 1) / BS), BS, 0, stream>>>(
        row_start, in_deg, csr_src, s_buf, b2, out, N);
}

// Round 17
// 154.953 us; speedup vs baseline: 1.8270x; 1.8270x over previous
//
#include <hip/hip_runtime.h>
#include <hip/hip_fp16.h>
#include <math.h>

// GCN 2-layer (DGL GraphConv norm='both'). SIX regular launches.
// r16 diagnostic decomposition: dur_us = ~90us harness poison-fills (2x268MB,
// retro-fits every round) + ~8us boundaries + our kernels (~57us): agg1~25
// (VALU-bound, 70% VALUBusy), K1~15, rowscan+partition+finalize+agg2~17.
// This round cuts agg1's VALU count: fp32 onorm[] precomputed in finalize
// (kills per-edge int-load+cvt+fmax+rsqrt chain), de-predicated edge loop
// (clamped always-execute loads + cndmask weights instead of exec-masked
// if-blocks; memory at 8% of peak has headroom). out_deg array removed.
// K1 regalloc-fragile (r7/r10 spills) -- byte-identical. Coop launch (r7/r8),
// SW barrier (r9), K1 grafting (r10) proven pathological; boundaries ~1-2us.
#define BS 256
#define EPB 2048    // edges per hist/partition block (8 iters of 256)

// ---- K1: per-block dst+src hists + featw1 (r6 verbatim) ----
__global__ __launch_bounds__(256, 4)
void histA_featw1_kernel(const int* __restrict__ src, const int* __restrict__ dst,
                         const float* __restrict__ feat, const float* __restrict__ W1,
                         int* __restrict__ dhist,
                         __half* __restrict__ featp,
                         int E, int N, int NB, int T, int M) {
    __shared__ float4 ftile[64 * 16];   // 64 feat rows (16KB)
    __shared__ int histD[256];
    __shared__ int histS[256];
    int tid = threadIdx.x;
    if ((int)blockIdx.x < T) {
        histD[tid] = 0; histS[tid] = 0;
        __syncthreads();
        int base = blockIdx.x * EPB;
        #pragma unroll
        for (int it = 0; it < EPB / BS; it++) {
            int e = base + it * BS + tid;
            if (e < E) {
                atomicAdd(&histD[dst[e] >> 8], 1);
                atomicAdd(&histS[src[e] >> 8], 1);
            }
        }
        __syncthreads();
        if (tid < NB) {
            dhist[tid * T + (int)blockIdx.x] = histD[tid];
            dhist[M + tid * T + (int)blockIdx.x] = histS[tid];
        }
    } else {
        int lane = tid & 63;
        int wave = tid >> 6;
        // W1 column for this lane: 64 named scalars (static -> registers).
        #define WD(i) float wv##i = W1[(i) * 64 + lane];
        WD(0)  WD(1)  WD(2)  WD(3)  WD(4)  WD(5)  WD(6)  WD(7)
        WD(8)  WD(9)  WD(10) WD(11) WD(12) WD(13) WD(14) WD(15)
        WD(16) WD(17) WD(18) WD(19) WD(20) WD(21) WD(22) WD(23)
        WD(24) WD(25) WD(26) WD(27) WD(28) WD(29) WD(30) WD(31)
        WD(32) WD(33) WD(34) WD(35) WD(36) WD(37) WD(38) WD(39)
        WD(40) WD(41) WD(42) WD(43) WD(44) WD(45) WD(46) WD(47)
        WD(48) WD(49) WD(50) WD(51) WD(52) WD(53) WD(54) WD(55)
        WD(56) WD(57) WD(58) WD(59) WD(60) WD(61) WD(62) WD(63)
        #undef WD
        // stage 64 feat rows into LDS (coalesced, 4 float4/thread)
        int rBase = ((int)blockIdx.x - T) * 64;
        const float4* feat4 = (const float4*)feat;
        int maxF4 = N * 16 - 1;
        #pragma unroll
        for (int it = 0; it < 4; it++) {
            int idx = it * BS + tid;
            ftile[idx] = feat4[min(rBase * 16 + idx, maxF4)];
        }
        __syncthreads();
        // 16 rows per wave; per row: 16 b128 broadcast reads + 64 FMA
        #pragma unroll 1
        for (int rr = 0; rr < 16; rr++) {
            int r = wave * 16 + rr;
            const float4* ft = &ftile[r * 16];
            float a0 = 0.0f, a1 = 0.0f, a2 = 0.0f, a3 = 0.0f;
            #define RK(k4, wA, wB, wC, wD_) { float4 f = ft[k4]; \
                a0 = fmaf(f.x, wA, a0); a1 = fmaf(f.y, wB, a1); \
                a2 = fmaf(f.z, wC, a2); a3 = fmaf(f.w, wD_, a3); }
            RK(0,  wv0,  wv1,  wv2,  wv3)  RK(1,  wv4,  wv5,  wv6,  wv7)
            RK(2,  wv8,  wv9,  wv10, wv11) RK(3,  wv12, wv13, wv14, wv15)
            RK(4,  wv16, wv17, wv18, wv19) RK(5,  wv20, wv21, wv22, wv23)
            RK(6,  wv24, wv25, wv26, wv27) RK(7,  wv28, wv29, wv30, wv31)
            RK(8,  wv32, wv33, wv34, wv35) RK(9,  wv36, wv37, wv38, wv39)
            RK(10, wv40, wv41, wv42, wv43) RK(11, wv44, wv45, wv46, wv47)
            RK(12, wv48, wv49, wv50, wv51) RK(13, wv52, wv53, wv54, wv55)
            RK(14, wv56, wv57, wv58, wv59) RK(15, wv60, wv61, wv62, wv63)
            #undef RK
            int rowg = rBase + r;
            if (rowg < N)
                featp[(size_t)rowg * 64 + lane] = __float2half((a0 + a1) + (a2 + a3));
        }
    }
}

// ---- K2: one wave per dhist row: in-place exclusive scan + rowTotal ----
__global__ void rowscan_kernel(int* __restrict__ dhist, int* __restrict__ rowTotal,
                               int T, int R) {
    int gw = (int)((blockIdx.x * blockDim.x + threadIdx.x) >> 6);
    int lane = threadIdx.x & 63;
    if (gw >= R) return;
    int* row = dhist + (size_t)gw * T;
    int carry = 0;
    int nch = (T + 63) >> 6;
    for (int c = 0; c < nch; c++) {
        int idx = c * 64 + lane;
        int v = (idx < T) ? row[idx] : 0;
        int inc = v;
        #pragma unroll
        for (int off = 1; off < 64; off <<= 1) {
            int u = __shfl_up(inc, off, 64);
            if (lane >= off) inc += u;
        }
        if (idx < T) row[idx] = inc - v + carry;   // exclusive within row
        carry += __shfl(inc, 63, 64);              // broadcast row-chunk total
    }
    if (lane == 0) rowTotal[gw] = carry;
}

// ---- K3: partition: redundant binBase scan + single-pass dual scatter ----
__global__ void partition_kernel(const int* __restrict__ src, const int* __restrict__ dst,
                                 const int* __restrict__ dhist, const int* __restrict__ rowTotal,
                                 int* __restrict__ packed, unsigned char* __restrict__ srcPartB,
                                 int E, int NB, int T, int M) {
    __shared__ int sd[256], ss[256];
    __shared__ int darr[256], sarr[256];
    int tid = threadIdx.x;
    int b = blockIdx.x;
    int vd = (tid < NB) ? rowTotal[tid] : 0;
    int vs = (tid < NB) ? rowTotal[NB + tid] : 0;
    sd[tid] = vd; ss[tid] = vs;
    __syncthreads();
    for (int off = 1; off < 256; off <<= 1) {
        int ud = (tid >= off) ? sd[tid - off] : 0;
        int us = (tid >= off) ? ss[tid - off] : 0;
        __syncthreads();
        sd[tid] += ud; ss[tid] += us;
        __syncthreads();
    }
    // base(bin,b) = binExcl[bin] + rowPref[bin][b]
    darr[tid] = (tid < NB) ? ((sd[tid] - vd) + dhist[tid * T + b]) : 0;
    sarr[tid] = (tid < NB) ? ((ss[tid] - vs) + dhist[M + tid * T + b]) : 0;
    __syncthreads();
    int base = b * EPB;
    #pragma unroll
    for (int it = 0; it < EPB / BS; it++) {
        int e = base + it * BS + tid;
        if (e < E) {
            int d = dst[e], s2 = src[e];
            int pos = atomicAdd(&darr[d >> 8], 1);
            packed[pos] = s2 | ((d & 255) << 17);
            int pos2 = atomicAdd(&sarr[s2 >> 8], 1);
            srcPartB[pos2] = (unsigned char)(s2 & 255);
        }
    }
}

// ---- K4: finalize: dst bins -> CSR; src bins -> fp32 onorm ----
__global__ void finalize_kernel(const int* __restrict__ rowTotal,
                                const int* __restrict__ packed,
                                const unsigned char* __restrict__ srcPartB,
                                int* __restrict__ csr_src, int* __restrict__ in_deg,
                                int* __restrict__ row_start, float* __restrict__ onorm,
                                int N, int NB) {
    __shared__ int sd[256], ss[256], td_[256], ts_[256];
    __shared__ int hist[256];
    __shared__ int sc[256];
    int tid = threadIdx.x;
    int b = blockIdx.x;
    int vd = (tid < NB) ? rowTotal[tid] : 0;
    int vs = (tid < NB) ? rowTotal[NB + tid] : 0;
    sd[tid] = vd; ss[tid] = vs; td_[tid] = vd; ts_[tid] = vs;
    __syncthreads();
    for (int off = 1; off < 256; off <<= 1) {
        int ud = (tid >= off) ? sd[tid - off] : 0;
        int us = (tid >= off) ? ss[tid - off] : 0;
        __syncthreads();
        sd[tid] += ud; ss[tid] += us;
        __syncthreads();
    }
    if (b < NB) {
        int lo = sd[b] - td_[b];       // exclusive binBase
        int hi = sd[b];                // inclusive = next bin's base
        hist[tid] = 0; __syncthreads();
        for (int i = lo + tid; i < hi; i += BS)
            atomicAdd(&hist[(packed[i] >> 17) & 255], 1);
        __syncthreads();
        int v = hist[tid];
        sc[tid] = v; __syncthreads();
        for (int off = 1; off < 256; off <<= 1) {
            int u = (tid >= off) ? sc[tid - off] : 0; __syncthreads();
            sc[tid] += u; __syncthreads();
        }
        int ex = sc[tid] - v;          // exclusive within bin
        int n = b * 256 + tid;
        if (n < N) { in_deg[n] = v; row_start[n] = lo + ex; }
        sc[tid] = lo + ex;             // becomes the scatter cursor
        __syncthreads();
        for (int i = lo + tid; i < hi; i += BS) {
            int pv = packed[i];
            int pos = atomicAdd(&sc[(pv >> 17) & 255], 1);
            csr_src[pos] = pv & 0x1FFFF;
        }
    } else {
        int sb = b - NB;
        int lo = ss[sb] - ts_[sb];
        int hi = ss[sb];
        hist[tid] = 0; __syncthreads();
        for (int i = lo + tid; i < hi; i += BS)
            atomicAdd(&hist[srcPartB[i]], 1);
        __syncthreads();
        int n = sb * 256 + tid;
        if (n < N) onorm[n] = rsqrtf(fmaxf((float)hist[tid], 1.0f));
    }
}

// ---- K5: agg1: one wave/node; de-predicated loop; onorm gathers ----
__global__ void csr_agg1_kernel(const int* __restrict__ row_start, const int* __restrict__ in_deg,
                                const int* __restrict__ csr_src, const float* __restrict__ onorm,
                                const __half* __restrict__ featp,
                                const float* __restrict__ b1, const float* __restrict__ W2,
                                float* __restrict__ s_buf, int N) {
    int gid = blockIdx.x * blockDim.x + threadIdx.x;
    int n = gid >> 6;
    if (n >= N) return;
    int lane = threadIdx.x & 63;
    int g = lane >> 3;   // edge slot within batch of 8
    int l = lane & 7;    // feature chunk: features [8l, 8l+8)
    int start = row_start[n];
    int deg = in_deg[n];
    float acc[8] = {0, 0, 0, 0, 0, 0, 0, 0};
    const uint4* fp4 = (const uint4*)featp;
    for (int j = 0; j < deg; j += 16) {
        int e0 = j + g;
        int e1 = e0 + 8;
        bool p0 = e0 < deg;
        bool p1 = e1 < deg;
        // clamped always-execute loads (no exec-masked blocks); weight = 0 kills tails
        int sn0 = csr_src[start + (p0 ? e0 : 0)];
        int sn1 = csr_src[start + (p1 ? e1 : 0)];
        uint4 q0 = fp4[(size_t)sn0 * 8 + l];
        uint4 q1 = fp4[(size_t)sn1 * 8 + l];
        float on0 = p0 ? onorm[sn0] : 0.0f;
        float on1 = p1 ? onorm[sn1] : 0.0f;
        const __half2* h0 = (const __half2*)&q0;
        const __half2* h1 = (const __half2*)&q1;
        #pragma unroll
        for (int c = 0; c < 4; c++) {
            float2 f0 = __half22float2(h0[c]);
            float2 f1 = __half22float2(h1[c]);
            acc[2 * c]     += on0 * f0.x + on1 * f1.x;
            acc[2 * c + 1] += on0 * f0.y + on1 * f1.y;
        }
    }
    #pragma unroll
    for (int off = 8; off < 64; off <<= 1) {
        #pragma unroll
        for (int c = 0; c < 8; c++)
            acc[c] += __shfl_xor(acc[c], off, 64);
    }
    float inn = rsqrtf(fmaxf((float)deg, 1.0f));
    float v = 0.0f;
    #pragma unroll
    for (int c = 0; c < 8; c++) {
        float h = fmaxf(inn * acc[c] + b1[l * 8 + c], 0.0f);
        v += h * W2[l * 8 + c];
    }
    #pragma unroll
    for (int off = 1; off < 8; off <<= 1)
        v += __shfl_xor(v, off, 64);
    if (lane == 0)
        s_buf[n] = onorm[n] * v;
}

// ---- K6: agg2: 16 lanes/node, unroll-2, sigmoid -> out ----
__global__ void csr_agg2_kernel(const int* __restrict__ row_start, const int* __restrict__ in_deg,
                                const int* __restrict__ csr_src,
                                const float* __restrict__ s_buf, const float* __restrict__ b2,
                                float* __restrict__ out, int N) {
    int gid = blockIdx.x * blockDim.x + threadIdx.x;
    int n = gid >> 4;
    if (n >= N) return;
    int sub = gid & 15;
    int start = row_start[n];
    int deg = in_deg[n];
    float a = 0.0f;
    for (int j = sub; j < deg; j += 32) {
        int j1 = j + 16;
        int i0 = csr_src[start + j];
        int i1 = (j1 < deg) ? csr_src[start + j1] : 0;
        float v0 = s_buf[i0];
        float v1 = (j1 < deg) ? s_buf[i1] : 0.0f;
        a += v0 + v1;
    }
    #pragma unroll
    for (int off = 1; off < 16; off <<= 1)
        a += __shfl_xor(a, off, 64);
    if (sub == 0) {
        float x = rsqrtf(fmaxf((float)deg, 1.0f)) * a + b2[0];
        out[n] = 1.0f / (1.0f + expf(-x));
    }
}

extern "C" void kernel_launch(void* const* d_in, const int* in_sizes, int n_in,
                              void* d_out, int out_size, void* d_ws, size_t ws_size,
                              hipStream_t stream) {
    const float* feat = (const float*)d_in[0];
    const float* W1   = (const float*)d_in[1];
    const float* b1   = (const float*)d_in[2];
    const float* W2   = (const float*)d_in[3];
    const float* b2   = (const float*)d_in[4];
    const int* src = (const int*)d_in[5];
    const int* dst = (const int*)d_in[6];
    float* out = (float*)d_out;

    const int N  = in_sizes[0] / 64;       // 50000
    const int E  = in_sizes[5];            // 800000
    const int NB = (N + 255) >> 8;         // 196 bins of 256 nodes
    const int T  = (E + EPB - 1) / EPB;    // 391 hist/partition blocks
    const int M  = NB * T;                 // per-side flat (bin, block) counts
    const int R  = 2 * NB;                 // dhist rows (dst bins then src bins)

    // workspace: rowTotal | per-node | dhist | edge arrays | fp16 | f32
    int* wsi = (int*)d_ws;
    int* rowTotal    = wsi;                          // 2*NB (written by rowscan)
    int* in_deg      = rowTotal + R;                 // N
    int* row_start   = in_deg + N;                   // N
    float* onorm     = (float*)(row_start + N);      // N (written by finalize)
    int* dhist       = (int*)(onorm + N);            // 2*M (fully overwritten)
    int* packed      = dhist + 2 * M;                // E
    int* csr_src     = packed + E;                   // E
    unsigned char* srcPartB = (unsigned char*)(csr_src + E);      // E bytes
    size_t int_bytes = ((size_t)R + 3 * (size_t)N + 2 * (size_t)M + 2 * (size_t)E) * sizeof(int)
                     + (size_t)E;
    size_t half_off  = (int_bytes + 15) & ~(size_t)15;
    __half* featp = (__half*)((char*)d_ws + half_off);            // 64N fp16
    float* s_buf  = (float*)((char*)d_ws + half_off + (size_t)64 * N * sizeof(__half));

    histA_featw1_kernel<<<T + (N + 63) / 64, BS, 0, stream>>>(
        src, dst, feat, W1, dhist, featp, E, N, NB, T, M);
    rowscan_kernel<<<(R * 64 + BS - 1) / BS, BS, 0, stream>>>(dhist, rowTotal, T, R);
    partition_kernel<<<T, BS, 0, stream>>>(
        src, dst, dhist, rowTotal, packed, srcPartB, E, NB, T, M);
    finalize_kernel<<<2 * NB, BS, 0, stream>>>(
        rowTotal, packed, srcPartB, csr_src, in_deg, row_start, onorm, N, NB);
    csr_agg1_kernel<<<(int)(((size_t)N * 64 + BS - 1) / BS), BS, 0, stream>>>(
        row_start, in_deg, csr_src, onorm, featp, b1, W2, s_buf, N);
    csr_agg2_kernel<<<(int)(((size_t)N * 16 + BS - 1) / BS), BS, 0, stream>>>(
        row_start, in_deg, csr_src, s_buf, b2, out, N);
}